// Round 2
// baseline (54718.048 us; speedup 1.0000x reference)
//
#include <hip/hip_runtime.h>
#include <stdint.h>

// ---------------------------------------------------------------------------
// 2-layer LSTM, T=1024 B=64 IC=HC=512, fp32 in/out, bf16 MFMA internally.
//
//   1. k_init_misc : Wi/Wh -> bf16, hbuf(par0) <- h0 (bf16), zero flag arrays
//   2. k_convert_x : x -> bf16
//   3. k_gemm_bias : xi1 = xbf @ Wi1^T + (bi1+bh1)   [bf16 out, 65536x2048]
//   4. k_recur(L0) : persistent, 1024 ticks, per-group FLAG barrier;
//                    writes h1 sequence (bf16) over xbf region, hT/cT(L0)
//   5. k_gemm_bias : xi2 = h1seq @ Wi2^T + (bi2+bh2)
//   6. k_recur(L1) : writes d_out h2 sequence (fp32) + hT/cT(L1)
//
// R2 change: the per-group device barrier is no longer a 32-way atomic
// counter (serialized cross-XCD RMWs ~18us/tick). Each block release-stores
// its own tick number into a private 128B-strided flag; wave 0 polls all 32
// flags in parallel with acquire loads. h/seq stores are nontemporal so the
// release fence's L2 writeback is near-empty.
// ---------------------------------------------------------------------------

typedef __attribute__((ext_vector_type(8))) short  bf16x8;
typedef __attribute__((ext_vector_type(4))) float  f32x4;
typedef __attribute__((address_space(1))) const void* as1cv;
typedef __attribute__((address_space(3))) void*       as3v;

#define T_STEPS 1024
#define GATES   2048

__device__ __forceinline__ float bf2f(unsigned short u) {
    union { unsigned int i; float f; } v; v.i = ((unsigned int)u) << 16; return v.f;
}
__device__ __forceinline__ unsigned short f2bf(float f) {
    union { float f; unsigned int i; } v; v.f = f;
    unsigned int x = v.i;
    x += 0x7fffu + ((x >> 16) & 1u);   // RNE
    return (unsigned short)(x >> 16);
}
__device__ __forceinline__ float sigmoidf_fast(float x) {
    return 1.f / (1.f + __expf(-x));
}
__device__ __forceinline__ float tanhf_fast(float x) {
    float e2 = __expf(2.f * x);        // inf/0 saturate correctly to +-1
    return 1.f - 2.f / (e2 + 1.f);
}

// ---------------------------------------------------------------- init -----
__global__ __launch_bounds__(256) void k_init_misc(
    const float* __restrict__ Wi, const float* __restrict__ Wh,
    const float* __restrict__ h0,
    unsigned short* __restrict__ Wib, unsigned short* __restrict__ Whb,
    unsigned short* __restrict__ hbufA, unsigned short* __restrict__ hbufB,
    unsigned int* __restrict__ barA, unsigned int* __restrict__ barB)
{
    int i = blockIdx.x * 256 + threadIdx.x;          // 0 .. 524287
    if (i < 524288) {                                // 2*2048*512 / 4
        const float4* wi4 = (const float4*)Wi;
        const float4* wh4 = (const float4*)Wh;
        float4 a = wi4[i], b = wh4[i];
        ((ushort4*)Wib)[i] = make_ushort4(f2bf(a.x), f2bf(a.y), f2bf(a.z), f2bf(a.w));
        ((ushort4*)Whb)[i] = make_ushort4(f2bf(b.x), f2bf(b.y), f2bf(b.z), f2bf(b.w));
    }
    if (i < 65536) {                                 // hbuf par0 <- h0 (both layers)
        int l = i >> 15, rem = i & 32767;
        int bg = rem >> 9, u = rem & 511;            // global batch, unit
        int gg = bg >> 3, bb = bg & 7;
        unsigned short v = f2bf(h0[l * 32768 + bg * 512 + u]);
        unsigned short* hb = l ? hbufB : hbufA;
        hb[(size_t)(gg * 8 + bb) * 512 + u] = v;     // par0 region
    }
    if (i < 16384) {                                 // zero flag arrays (8KB u32 each)
        if (i < 8192) barA[i] = 0u; else barB[i - 8192] = 0u;
    }
}

__global__ __launch_bounds__(256) void k_convert_x(
    const float* __restrict__ x, unsigned short* __restrict__ xbf, int n4)
{
    int i = blockIdx.x * 256 + threadIdx.x;
    if (i >= n4) return;
    float4 v = ((const float4*)x)[i];
    ((ushort4*)xbf)[i] = make_ushort4(f2bf(v.x), f2bf(v.y), f2bf(v.z), f2bf(v.w));
}

// ---------------------------------------------------------------- GEMM -----
// C[m][n] = sum_k A[m][k]*W[n][k] + bi[n] + bh[n];  A:[M][512], W:[2048][512]
// M=65536, N=2048, K=512. 128x128 tile, BK=64, 4 waves (2x2), 4x4 acc/wave.
__global__ __launch_bounds__(256) void k_gemm_bias(
    const unsigned short* __restrict__ A,
    const unsigned short* __restrict__ W,
    const float* __restrict__ bi, const float* __restrict__ bh,
    unsigned short* __restrict__ Cout)
{
    __shared__ unsigned short As[128 * 64];
    __shared__ unsigned short Bs[128 * 64];
    const int NB = GATES / 128;                      // 16
    int bn = blockIdx.x % NB, bm = blockIdx.x / NB;
    int m0 = bm * 128, n0 = bn * 128;
    int tid = threadIdx.x, lane = tid & 63, w = tid >> 6;
    int wr = w >> 1, wc = w & 1;

    f32x4 acc[4][4];
    #pragma unroll
    for (int a = 0; a < 4; ++a)
        #pragma unroll
        for (int b = 0; b < 4; ++b) { f32x4 z = {0.f,0.f,0.f,0.f}; acc[a][b] = z; }

    for (int kt = 0; kt < 8; ++kt) {
        int k0 = kt * 64;
        __syncthreads();                              // protect LDS reuse
        #pragma unroll
        for (int i = 0; i < 4; ++i) {                 // stage As (16 KB)
            int lin = (w * 4 + i) * 1024 + lane * 16; // byte pos
            int row = lin >> 7;
            int p   = (lin & 127) >> 4;
            int c   = p ^ (row & 7);
            const unsigned short* ga = A + (size_t)(m0 + row) * 512 + k0 + c * 8;
            __builtin_amdgcn_global_load_lds((as1cv)ga, (as3v)((char*)As + lin), 16, 0, 0);
        }
        #pragma unroll
        for (int i = 0; i < 4; ++i) {                 // stage Bs (16 KB)
            int lin = (w * 4 + i) * 1024 + lane * 16;
            int row = lin >> 7;
            int p   = (lin & 127) >> 4;
            int c   = p ^ (row & 7);
            const unsigned short* gb = W + (size_t)(n0 + row) * 512 + k0 + c * 8;
            __builtin_amdgcn_global_load_lds((as1cv)gb, (as3v)((char*)Bs + lin), 16, 0, 0);
        }
        __syncthreads();
        #pragma unroll
        for (int ks = 0; ks < 2; ++ks) {
            bf16x8 af[4], bfr[4];
            #pragma unroll
            for (int mt = 0; mt < 4; ++mt) {
                int row = wr * 64 + mt * 16 + (lane & 15);
                int p = (ks * 4 + (lane >> 4)) ^ (row & 7);
                af[mt] = *(const bf16x8*)(&As[row * 64 + p * 8]);
            }
            #pragma unroll
            for (int nt = 0; nt < 4; ++nt) {
                int row = wc * 64 + nt * 16 + (lane & 15);
                int p = (ks * 4 + (lane >> 4)) ^ (row & 7);
                bfr[nt] = *(const bf16x8*)(&Bs[row * 64 + p * 8]);
            }
            #pragma unroll
            for (int mt = 0; mt < 4; ++mt)
                #pragma unroll
                for (int nt = 0; nt < 4; ++nt)
                    acc[mt][nt] = __builtin_amdgcn_mfma_f32_16x16x32_bf16(
                        af[mt], bfr[nt], acc[mt][nt], 0, 0, 0);
        }
    }
    // epilogue: C row = (lane>>4)*4+reg, col = lane&15  [m89-verified]
    #pragma unroll
    for (int nt = 0; nt < 4; ++nt) {
        int n = n0 + wc * 64 + nt * 16 + (lane & 15);
        float bias = bi[n] + bh[n];
        #pragma unroll
        for (int mt = 0; mt < 4; ++mt) {
            #pragma unroll
            for (int r = 0; r < 4; ++r) {
                int m = m0 + wr * 64 + mt * 16 + (lane >> 4) * 4 + r;
                Cout[(size_t)m * GATES + n] = f2bf(acc[mt][nt][r] + bias);
            }
        }
    }
}

// --------------------------------------------------------------- recur -----
// grid 256: group g = blockIdx&7 (8 batches), j = blockIdx>>3 (16 units).
// Flag barrier: bar[g*1024 + j*32] holds the last tick this block finished.
__global__ __launch_bounds__(256) void k_recur(
    const unsigned short* __restrict__ Wh,    // layer's [2048][512] bf16
    const unsigned short* __restrict__ xi,    // [T*64][2048] bf16 (biases folded)
    const float* __restrict__ c0,             // layer's [64][512]
    unsigned short* __restrict__ hbuf,        // [2 par][8 grp][8 b][512] bf16
    unsigned int* __restrict__ bar,           // [8 grp][32 blk][32 u32 pad]
    unsigned short* __restrict__ seq_bf,      // layer0: h1 seq out (or null)
    float* __restrict__ seq_f32,              // layer1: d_out h2 seq (or null)
    float* __restrict__ hT, float* __restrict__ cT)   // [64][512]
{
    __shared__ unsigned short hA[16 * 512];   // swizzled h tile (rows 8..15 = 0)
    __shared__ float gAcc[4][16][17];         // [seg][batch 0..15][unit 0..15]

    const int g = blockIdx.x & 7;
    const int j = blockIdx.x >> 3;
    const int tid = threadIdx.x;
    const int lane = tid & 63;
    const int w = tid >> 6;                   // wave == gate segment

    for (int i = tid; i < 16 * 512; i += 256) hA[i] = 0;

    // Persistent Wh fragments: wave w, units 16j..16j+15, seg w, all K.
    bf16x8 wB[16];
    {
        int n = lane & 15;
        int rowW = w * 512 + 16 * j + n;
        int kq = (lane >> 4) * 8;
        #pragma unroll
        for (int ks = 0; ks < 16; ++ks)
            wB[ks] = *(const bf16x8*)(Wh + (size_t)rowW * 512 + ks * 32 + kq);
    }

    // elementwise pair state (threads 0..127): one (unit,batch) per thread
    const int pb = (tid >> 4) & 7;            // local batch 0..7
    const int pu = tid & 15;                  // local unit 0..15
    const int bglob = 8 * g + pb;
    const int uglob = 16 * j + pu;
    float c = 0.f;
    unsigned short xc0 = 0, xc1 = 0, xc2 = 0, xc3 = 0;
    if (tid < 128) {
        c = c0[bglob * 512 + uglob];
        const unsigned short* xr = xi + (size_t)bglob * GATES;
        xc0 = xr[uglob]; xc1 = xr[512 + uglob]; xc2 = xr[1024 + uglob]; xc3 = xr[1536 + uglob];
    }
    __syncthreads();

    unsigned int* gb    = bar + g * 1024;     // this group's 32 flags (128B apart)
    unsigned int* myfl  = gb + j * 32;

    for (int t = 0; t < T_STEPS; ++t) {
        const int par = t & 1;
        // stage h(t-1): 8 rows x 512 bf16, XOR-swizzled 16B chunks
        {
            const unsigned short* src = hbuf + ((size_t)par * 8 + g) * (8 * 512);
            #pragma unroll
            for (int i = 0; i < 2; ++i) {
                int lin = i * 4096 + tid * 16;          // byte pos in 8KB
                int row = lin >> 10;
                int p   = (lin & 1023) >> 4;
                int cch = p ^ (row & 7);
                const unsigned short* gsrc = src + row * 512 + cch * 8;
                __builtin_amdgcn_global_load_lds((as1cv)gsrc, (as3v)((char*)hA + lin), 16, 0, 0);
            }
        }
        // prefetch next tick's xi (hidden under MFMA phase)
        unsigned short xn0 = 0, xn1 = 0, xn2 = 0, xn3 = 0;
        if (tid < 128) {
            int tn = (t + 1 < T_STEPS) ? t + 1 : t;
            const unsigned short* xr = xi + (size_t)(tn * 64 + bglob) * GATES;
            xn0 = xr[uglob]; xn1 = xr[512 + uglob]; xn2 = xr[1024 + uglob]; xn3 = xr[1536 + uglob];
        }
        __syncthreads();

        // MFMA: one 16x16 tile per wave, K=512 as two independent 8-chains
        {
            f32x4 accA = {0.f,0.f,0.f,0.f}, accB = {0.f,0.f,0.f,0.f};
            int m  = lane & 15;
            #pragma unroll
            for (int ks = 0; ks < 8; ++ks) {
                int p = ((ks * 4 + (lane >> 4)) ^ (m & 7));
                bf16x8 a = *(const bf16x8*)(&hA[m * 512 + p * 8]);
                accA = __builtin_amdgcn_mfma_f32_16x16x32_bf16(a, wB[ks], accA, 0, 0, 0);
            }
            #pragma unroll
            for (int ks = 8; ks < 16; ++ks) {
                int p = ((ks * 4 + (lane >> 4)) ^ (m & 7));
                bf16x8 a = *(const bf16x8*)(&hA[m * 512 + p * 8]);
                accB = __builtin_amdgcn_mfma_f32_16x16x32_bf16(a, wB[ks], accB, 0, 0, 0);
            }
            f32x4 acc = accA + accB;
            int mrow = (lane >> 4) * 4, ncol = lane & 15;
            #pragma unroll
            for (int r = 0; r < 4; ++r) gAcc[w][mrow + r][ncol] = acc[r];
        }
        __syncthreads();

        // elementwise gate math + state update; nt-store h to exchange buffer
        float h = 0.f;
        if (tid < 128) {
            float fpre = gAcc[0][pb][pu] + bf2f(xc0);
            float ipre = gAcc[1][pb][pu] + bf2f(xc1);
            float opre = gAcc[2][pb][pu] + bf2f(xc2);
            float gpre = gAcc[3][pb][pu] + bf2f(xc3);
            float fg = sigmoidf_fast(fpre);
            float ig = sigmoidf_fast(ipre);
            float og = sigmoidf_fast(opre);
            float gg = tanhf_fast(gpre);
            c = c * fg + gg * ig;
            h = og * tanhf_fast(c);
            __builtin_nontemporal_store(f2bf(h),
                &hbuf[((size_t)(par ^ 1) * 8 + g) * (8 * 512) + pb * 512 + uglob]);
        }
        __syncthreads();                      // drains all threads' h stores

        // arrive: one release store (wbl2 flushes any dirty L2 lines)
        if (tid == 0)
            __hip_atomic_store(myfl, (unsigned int)(t + 1), __ATOMIC_RELEASE,
                               __HIP_MEMORY_SCOPE_AGENT);

        // off-critical-path: sequence/final outputs + xi register rotate
        if (tid < 128) {
            if (seq_bf)
                __builtin_nontemporal_store(f2bf(h),
                    &seq_bf[(size_t)(t * 64 + bglob) * 512 + uglob]);
            if (seq_f32)
                __builtin_nontemporal_store(h,
                    &seq_f32[(size_t)(t * 64 + bglob) * 512 + uglob]);
            if (t == T_STEPS - 1) {
                hT[bglob * 512 + uglob] = h;
                cT[bglob * 512 + uglob] = c;
            }
            xc0 = xn0; xc1 = xn1; xc2 = xn2; xc3 = xn3;
        }

        // wait: wave 0 polls all 32 flags in parallel (2 lanes/flag)
        if (tid < 64) {
            const unsigned int tgt = (unsigned int)(t + 1);
            unsigned int* fl = gb + (tid & 31) * 32;
            while (__hip_atomic_load(fl, __ATOMIC_ACQUIRE,
                                     __HIP_MEMORY_SCOPE_AGENT) < tgt) {
                __builtin_amdgcn_s_sleep(1);
            }
        }
        __threadfence();                      // inv stale L1/L2 before h reads
        __syncthreads();
    }
}

// --------------------------------------------------------------- launch ----
extern "C" void kernel_launch(void* const* d_in, const int* in_sizes, int n_in,
                              void* d_out, int out_size, void* d_ws, size_t ws_size,
                              hipStream_t stream)
{
    (void)in_sizes; (void)n_in; (void)out_size; (void)ws_size;
    const float* x  = (const float*)d_in[0];   // [1024,64,512]
    const float* Wi = (const float*)d_in[1];   // [2,2048,512]
    const float* bi = (const float*)d_in[2];   // [2,2048]
    const float* Wh = (const float*)d_in[3];   // [2,2048,512]
    const float* bh = (const float*)d_in[4];   // [2,2048]
    const float* h0 = (const float*)d_in[5];   // [2,64,512]
    const float* c0 = (const float*)d_in[6];   // [2,64,512]
    float* out = (float*)d_out;

    char* ws = (char*)d_ws;
    const size_t OFF_XI  = 67108864;                    // xbf/h1seq: 64 MB
    const size_t OFF_WIB = OFF_XI  + 268435456;         // xi: 256 MB
    const size_t OFF_WHB = OFF_WIB + 4194304;
    const size_t OFF_HBA = OFF_WHB + 4194304;
    const size_t OFF_HBB = OFF_HBA + 131072;
    const size_t OFF_BRA = OFF_HBB + 131072;            // 32 KB flags (L0)
    const size_t OFF_BRB = OFF_BRA + 32768;             // 32 KB flags (L1)

    unsigned short* xbf   = (unsigned short*)(ws);      // reused as h1seq
    unsigned short* xi    = (unsigned short*)(ws + OFF_XI);
    unsigned short* Wib   = (unsigned short*)(ws + OFF_WIB);
    unsigned short* Whb   = (unsigned short*)(ws + OFF_WHB);
    unsigned short* hbufA = (unsigned short*)(ws + OFF_HBA);
    unsigned short* hbufB = (unsigned short*)(ws + OFF_HBB);
    unsigned int*   barA  = (unsigned int*)(ws + OFF_BRA);
    unsigned int*   barB  = (unsigned int*)(ws + OFF_BRB);

    const size_t SEQ = 33554432;                        // T*B*HC
    float* hs = out + SEQ;                              // [2,64,512]
    float* cs = out + SEQ + 65536;                      // [2,64,512]

    k_init_misc<<<2048, 256, 0, stream>>>(Wi, Wh, h0, Wib, Whb, hbufA, hbufB, barA, barB);
    k_convert_x<<<32768, 256, 0, stream>>>(x, xbf, 8388608);

    // layer 0
    k_gemm_bias<<<8192, 256, 0, stream>>>(xbf, Wib, bi, bh, xi);
    k_recur<<<256, 256, 0, stream>>>(Whb, xi, c0, hbufA, barA,
                                     /*seq_bf=*/xbf, /*seq_f32=*/nullptr,
                                     hs, cs);
    // layer 1
    k_gemm_bias<<<8192, 256, 0, stream>>>(xbf /*h1seq*/, Wib + 2048 * 512,
                                          bi + 2048, bh + 2048, xi);
    k_recur<<<256, 256, 0, stream>>>(Whb + 2048 * 512, xi, c0 + 32768, hbufB, barB,
                                     /*seq_bf=*/nullptr, /*seq_f32=*/out,
                                     hs + 32768, cs + 32768);
}

// Round 3
// 7607.648 us; speedup vs baseline: 7.1925x; 7.1925x over previous
//
#include <hip/hip_runtime.h>
#include <stdint.h>

// ---------------------------------------------------------------------------
// 2-layer LSTM, T=1024 B=64 IC=HC=512, fp32 in/out, bf16 MFMA internally.
//
//   1. k_init_misc : Wi/Wh -> bf16, hbuf(par0) <- h0 (bf16), zero flag arrays
//   2. k_convert_x : x -> bf16
//   3. k_gemm_bias : xi1 = xbf @ Wi1^T + (bi1+bh1)   [bf16 out, 65536x2048]
//   4. k_recur(L0) : persistent, 1024 ticks, per-group FLAG barrier;
//                    writes h1 sequence (bf16) over xbf region, hT/cT(L0)
//   5. k_gemm_bias : xi2 = h1seq @ Wi2^T + (bi2+bh2)
//   6. k_recur(L1) : writes d_out h2 sequence (fp32) + hT/cT(L1)
//
// R3 change: eliminate per-tick cache-maintenance storms. R1/R2 spun on
// ACQUIRE loads (each emits buffer_inv -> thousands of L1/L2 invalidates per
// tick per XCD) and fenced with threadfence/release (buffer_wbl2 scans).
// Now: h exchange = RELAXED agent atomic stores (write-through to MALL),
// drained by __syncthreads' vmcnt(0); flag arrive = RELAXED store; wait =
// RELAXED polls (bare coherence-point loads, no inv); then EXACTLY ONE
// acquire fence per tick per block before re-staging h. seq outputs are
// plain cached stores. xi prefetch issued under the barrier wait.
// ---------------------------------------------------------------------------

typedef __attribute__((ext_vector_type(8))) short  bf16x8;
typedef __attribute__((ext_vector_type(4))) float  f32x4;
typedef __attribute__((address_space(1))) const void* as1cv;
typedef __attribute__((address_space(3))) void*       as3v;

#define T_STEPS 1024
#define GATES   2048

__device__ __forceinline__ float bf2f(unsigned short u) {
    union { unsigned int i; float f; } v; v.i = ((unsigned int)u) << 16; return v.f;
}
__device__ __forceinline__ unsigned short f2bf(float f) {
    union { float f; unsigned int i; } v; v.f = f;
    unsigned int x = v.i;
    x += 0x7fffu + ((x >> 16) & 1u);   // RNE
    return (unsigned short)(x >> 16);
}
__device__ __forceinline__ float sigmoidf_fast(float x) {
    return 1.f / (1.f + __expf(-x));
}
__device__ __forceinline__ float tanhf_fast(float x) {
    float e2 = __expf(2.f * x);        // inf/0 saturate correctly to +-1
    return 1.f - 2.f / (e2 + 1.f);
}

// ---------------------------------------------------------------- init -----
__global__ __launch_bounds__(256) void k_init_misc(
    const float* __restrict__ Wi, const float* __restrict__ Wh,
    const float* __restrict__ h0,
    unsigned short* __restrict__ Wib, unsigned short* __restrict__ Whb,
    unsigned short* __restrict__ hbufA, unsigned short* __restrict__ hbufB,
    unsigned int* __restrict__ barA, unsigned int* __restrict__ barB)
{
    int i = blockIdx.x * 256 + threadIdx.x;          // 0 .. 524287
    if (i < 524288) {                                // 2*2048*512 / 4
        const float4* wi4 = (const float4*)Wi;
        const float4* wh4 = (const float4*)Wh;
        float4 a = wi4[i], b = wh4[i];
        ((ushort4*)Wib)[i] = make_ushort4(f2bf(a.x), f2bf(a.y), f2bf(a.z), f2bf(a.w));
        ((ushort4*)Whb)[i] = make_ushort4(f2bf(b.x), f2bf(b.y), f2bf(b.z), f2bf(b.w));
    }
    if (i < 65536) {                                 // hbuf par0 <- h0 (both layers)
        int l = i >> 15, rem = i & 32767;
        int bg = rem >> 9, u = rem & 511;            // global batch, unit
        int gg = bg >> 3, bb = bg & 7;
        unsigned short v = f2bf(h0[l * 32768 + bg * 512 + u]);
        unsigned short* hb = l ? hbufB : hbufA;
        hb[(size_t)(gg * 8 + bb) * 512 + u] = v;     // par0 region
    }
    if (i < 16384) {                                 // zero flag arrays (8K u32 each)
        if (i < 8192) barA[i] = 0u; else barB[i - 8192] = 0u;
    }
}

__global__ __launch_bounds__(256) void k_convert_x(
    const float* __restrict__ x, unsigned short* __restrict__ xbf, int n4)
{
    int i = blockIdx.x * 256 + threadIdx.x;
    if (i >= n4) return;
    float4 v = ((const float4*)x)[i];
    ((ushort4*)xbf)[i] = make_ushort4(f2bf(v.x), f2bf(v.y), f2bf(v.z), f2bf(v.w));
}

// ---------------------------------------------------------------- GEMM -----
// C[m][n] = sum_k A[m][k]*W[n][k] + bi[n] + bh[n];  A:[M][512], W:[2048][512]
// M=65536, N=2048, K=512. 128x128 tile, BK=64, 4 waves (2x2), 4x4 acc/wave.
__global__ __launch_bounds__(256) void k_gemm_bias(
    const unsigned short* __restrict__ A,
    const unsigned short* __restrict__ W,
    const float* __restrict__ bi, const float* __restrict__ bh,
    unsigned short* __restrict__ Cout)
{
    __shared__ unsigned short As[128 * 64];
    __shared__ unsigned short Bs[128 * 64];
    const int NB = GATES / 128;                      // 16
    int bn = blockIdx.x % NB, bm = blockIdx.x / NB;
    int m0 = bm * 128, n0 = bn * 128;
    int tid = threadIdx.x, lane = tid & 63, w = tid >> 6;
    int wr = w >> 1, wc = w & 1;

    f32x4 acc[4][4];
    #pragma unroll
    for (int a = 0; a < 4; ++a)
        #pragma unroll
        for (int b = 0; b < 4; ++b) { f32x4 z = {0.f,0.f,0.f,0.f}; acc[a][b] = z; }

    for (int kt = 0; kt < 8; ++kt) {
        int k0 = kt * 64;
        __syncthreads();                              // protect LDS reuse
        #pragma unroll
        for (int i = 0; i < 4; ++i) {                 // stage As (16 KB)
            int lin = (w * 4 + i) * 1024 + lane * 16; // byte pos
            int row = lin >> 7;
            int p   = (lin & 127) >> 4;
            int c   = p ^ (row & 7);
            const unsigned short* ga = A + (size_t)(m0 + row) * 512 + k0 + c * 8;
            __builtin_amdgcn_global_load_lds((as1cv)ga, (as3v)((char*)As + lin), 16, 0, 0);
        }
        #pragma unroll
        for (int i = 0; i < 4; ++i) {                 // stage Bs (16 KB)
            int lin = (w * 4 + i) * 1024 + lane * 16;
            int row = lin >> 7;
            int p   = (lin & 127) >> 4;
            int c   = p ^ (row & 7);
            const unsigned short* gb = W + (size_t)(n0 + row) * 512 + k0 + c * 8;
            __builtin_amdgcn_global_load_lds((as1cv)gb, (as3v)((char*)Bs + lin), 16, 0, 0);
        }
        __syncthreads();
        #pragma unroll
        for (int ks = 0; ks < 2; ++ks) {
            bf16x8 af[4], bfr[4];
            #pragma unroll
            for (int mt = 0; mt < 4; ++mt) {
                int row = wr * 64 + mt * 16 + (lane & 15);
                int p = (ks * 4 + (lane >> 4)) ^ (row & 7);
                af[mt] = *(const bf16x8*)(&As[row * 64 + p * 8]);
            }
            #pragma unroll
            for (int nt = 0; nt < 4; ++nt) {
                int row = wc * 64 + nt * 16 + (lane & 15);
                int p = (ks * 4 + (lane >> 4)) ^ (row & 7);
                bfr[nt] = *(const bf16x8*)(&Bs[row * 64 + p * 8]);
            }
            #pragma unroll
            for (int mt = 0; mt < 4; ++mt)
                #pragma unroll
                for (int nt = 0; nt < 4; ++nt)
                    acc[mt][nt] = __builtin_amdgcn_mfma_f32_16x16x32_bf16(
                        af[mt], bfr[nt], acc[mt][nt], 0, 0, 0);
        }
    }
    // epilogue: C row = (lane>>4)*4+reg, col = lane&15  [m89-verified]
    #pragma unroll
    for (int nt = 0; nt < 4; ++nt) {
        int n = n0 + wc * 64 + nt * 16 + (lane & 15);
        float bias = bi[n] + bh[n];
        #pragma unroll
        for (int mt = 0; mt < 4; ++mt) {
            #pragma unroll
            for (int r = 0; r < 4; ++r) {
                int m = m0 + wr * 64 + mt * 16 + (lane >> 4) * 4 + r;
                Cout[(size_t)m * GATES + n] = f2bf(acc[mt][nt][r] + bias);
            }
        }
    }
}

// --------------------------------------------------------------- recur -----
// grid 256: group g = blockIdx&7 (8 batches), j = blockIdx>>3 (16 units).
// Flag barrier: bar[g*1024 + j*32] holds the last tick block (g,j) finished.
__global__ __launch_bounds__(256) void k_recur(
    const unsigned short* __restrict__ Wh,    // layer's [2048][512] bf16
    const unsigned short* __restrict__ xi,    // [T*64][2048] bf16 (biases folded)
    const float* __restrict__ c0,             // layer's [64][512]
    unsigned short* __restrict__ hbuf,        // [2 par][8 grp][8 b][512] bf16
    unsigned int* __restrict__ bar,           // [8 grp][32 blk][32 u32 pad]
    unsigned short* __restrict__ seq_bf,      // layer0: h1 seq out (or null)
    float* __restrict__ seq_f32,              // layer1: d_out h2 seq (or null)
    float* __restrict__ hT, float* __restrict__ cT)   // [64][512]
{
    __shared__ unsigned short hA[16 * 512];   // swizzled h tile (rows 8..15 = 0)
    __shared__ float gAcc[4][16][17];         // [seg][batch 0..15][unit 0..15]

    const int g = blockIdx.x & 7;
    const int j = blockIdx.x >> 3;
    const int tid = threadIdx.x;
    const int lane = tid & 63;
    const int w = tid >> 6;                   // wave == gate segment

    for (int i = tid; i < 16 * 512; i += 256) hA[i] = 0;

    // Persistent Wh fragments: wave w, units 16j..16j+15, seg w, all K.
    bf16x8 wB[16];
    {
        int n = lane & 15;
        int rowW = w * 512 + 16 * j + n;
        int kq = (lane >> 4) * 8;
        #pragma unroll
        for (int ks = 0; ks < 16; ++ks)
            wB[ks] = *(const bf16x8*)(Wh + (size_t)rowW * 512 + ks * 32 + kq);
    }

    // elementwise pair state (threads 0..127): one (unit,batch) per thread
    const int pb = (tid >> 4) & 7;            // local batch 0..7
    const int pu = tid & 15;                  // local unit 0..15
    const int bglob = 8 * g + pb;
    const int uglob = 16 * j + pu;
    float c = 0.f;
    unsigned short xc0 = 0, xc1 = 0, xc2 = 0, xc3 = 0;
    if (tid < 128) {
        c = c0[bglob * 512 + uglob];
        const unsigned short* xr = xi + (size_t)bglob * GATES;
        xc0 = xr[uglob]; xc1 = xr[512 + uglob]; xc2 = xr[1024 + uglob]; xc3 = xr[1536 + uglob];
    }
    __syncthreads();

    unsigned int* gbf  = bar + g * 1024;      // this group's 32 flags (128B apart)
    unsigned int* myfl = gbf + j * 32;

    for (int t = 0; t < T_STEPS; ++t) {
        const int par = t & 1;

        // [A] stage h(t-1): 8 rows x 512 bf16, XOR-swizzled 16B chunks.
        // Caches were invalidated by last tick's single acquire fence.
        {
            const unsigned short* src = hbuf + ((size_t)par * 8 + g) * (8 * 512);
            #pragma unroll
            for (int i = 0; i < 2; ++i) {
                int lin = i * 4096 + tid * 16;          // byte pos in 8KB
                int row = lin >> 10;
                int p   = (lin & 1023) >> 4;
                int cch = p ^ (row & 7);
                const unsigned short* gsrc = src + row * 512 + cch * 8;
                __builtin_amdgcn_global_load_lds((as1cv)gsrc, (as3v)((char*)hA + lin), 16, 0, 0);
            }
        }
        __syncthreads();                      // [B] drains staging (vmcnt0)

        // [C] MFMA: one 16x16 tile per wave, K=512 as two independent 8-chains
        {
            f32x4 accA = {0.f,0.f,0.f,0.f}, accB = {0.f,0.f,0.f,0.f};
            int m  = lane & 15;
            #pragma unroll
            for (int ks = 0; ks < 8; ++ks) {
                int p = ((ks * 4 + (lane >> 4)) ^ (m & 7));
                bf16x8 a = *(const bf16x8*)(&hA[m * 512 + p * 8]);
                accA = __builtin_amdgcn_mfma_f32_16x16x32_bf16(a, wB[ks], accA, 0, 0, 0);
            }
            #pragma unroll
            for (int ks = 8; ks < 16; ++ks) {
                int p = ((ks * 4 + (lane >> 4)) ^ (m & 7));
                bf16x8 a = *(const bf16x8*)(&hA[m * 512 + p * 8]);
                accB = __builtin_amdgcn_mfma_f32_16x16x32_bf16(a, wB[ks], accB, 0, 0, 0);
            }
            f32x4 acc = accA + accB;
            int mrow = (lane >> 4) * 4, ncol = lane & 15;
            #pragma unroll
            for (int r = 0; r < 4; ++r) gAcc[w][mrow + r][ncol] = acc[r];
        }
        __syncthreads();                      // [D] gAcc visible block-wide

        // [E] gate math + state update; h -> hbuf via RELAXED agent atomic
        // store (write-through to coherence point, no wbl2, no inv).
        float h = 0.f;
        if (tid < 128) {
            float fpre = gAcc[0][pb][pu] + bf2f(xc0);
            float ipre = gAcc[1][pb][pu] + bf2f(xc1);
            float opre = gAcc[2][pb][pu] + bf2f(xc2);
            float gpre = gAcc[3][pb][pu] + bf2f(xc3);
            float fg = sigmoidf_fast(fpre);
            float ig = sigmoidf_fast(ipre);
            float og = sigmoidf_fast(opre);
            float gg = tanhf_fast(gpre);
            c = c * fg + gg * ig;
            h = og * tanhf_fast(c);
            __hip_atomic_store(
                &hbuf[((size_t)(par ^ 1) * 8 + g) * (8 * 512) + pb * 512 + uglob],
                f2bf(h), __ATOMIC_RELAXED, __HIP_MEMORY_SCOPE_AGENT);
        }
        __syncthreads();                      // [F] vmcnt(0): h stores are
                                              // complete at coherence point

        // [G] arrive: bare write-through store, no fence instructions
        if (tid == 0)
            __hip_atomic_store(myfl, (unsigned int)(t + 1), __ATOMIC_RELAXED,
                               __HIP_MEMORY_SCOPE_AGENT);

        // [H] off-critical-path: seq/final outputs (plain cached stores) and
        // next-tick xi prefetch, all in flight during the barrier wait.
        unsigned short xn0 = 0, xn1 = 0, xn2 = 0, xn3 = 0;
        if (tid < 128) {
            if (seq_bf)
                seq_bf[(size_t)(t * 64 + bglob) * 512 + uglob] = f2bf(h);
            if (seq_f32)
                seq_f32[(size_t)(t * 64 + bglob) * 512 + uglob] = h;
            if (t == T_STEPS - 1) {
                hT[bglob * 512 + uglob] = h;
                cT[bglob * 512 + uglob] = c;
            }
            int tn = (t + 1 < T_STEPS) ? t + 1 : t;
            const unsigned short* xr = xi + (size_t)(tn * 64 + bglob) * GATES;
            xn0 = xr[uglob]; xn1 = xr[512 + uglob]; xn2 = xr[1024 + uglob]; xn3 = xr[1536 + uglob];
        }

        // [I] wait: wave 0 polls all 32 flags with RELAXED loads (bare
        // coherence-point reads, NO invalidate per iteration), then issues
        // exactly ONE acquire fence to invalidate stale L1/L2 before [A].
        if (tid < 64) {
            const unsigned int tgt = (unsigned int)(t + 1);
            unsigned int* fl = gbf + (tid & 31) * 32;
            while (__hip_atomic_load(fl, __ATOMIC_RELAXED,
                                     __HIP_MEMORY_SCOPE_AGENT) < tgt) {
                __builtin_amdgcn_s_sleep(2);
            }
            __builtin_amdgcn_fence(__ATOMIC_ACQUIRE, "agent");
        }
        if (tid < 128) { xc0 = xn0; xc1 = xn1; xc2 = xn2; xc3 = xn3; }
        __syncthreads();                      // [J] all waves held until inv done
    }
}

// --------------------------------------------------------------- launch ----
extern "C" void kernel_launch(void* const* d_in, const int* in_sizes, int n_in,
                              void* d_out, int out_size, void* d_ws, size_t ws_size,
                              hipStream_t stream)
{
    (void)in_sizes; (void)n_in; (void)out_size; (void)ws_size;
    const float* x  = (const float*)d_in[0];   // [1024,64,512]
    const float* Wi = (const float*)d_in[1];   // [2,2048,512]
    const float* bi = (const float*)d_in[2];   // [2,2048]
    const float* Wh = (const float*)d_in[3];   // [2,2048,512]
    const float* bh = (const float*)d_in[4];   // [2,2048]
    const float* h0 = (const float*)d_in[5];   // [2,64,512]
    const float* c0 = (const float*)d_in[6];   // [2,64,512]
    float* out = (float*)d_out;

    char* ws = (char*)d_ws;
    const size_t OFF_XI  = 67108864;                    // xbf/h1seq: 64 MB
    const size_t OFF_WIB = OFF_XI  + 268435456;         // xi: 256 MB
    const size_t OFF_WHB = OFF_WIB + 4194304;
    const size_t OFF_HBA = OFF_WHB + 4194304;
    const size_t OFF_HBB = OFF_HBA + 131072;
    const size_t OFF_BRA = OFF_HBB + 131072;            // 32 KB flags (L0)
    const size_t OFF_BRB = OFF_BRA + 32768;             // 32 KB flags (L1)

    unsigned short* xbf   = (unsigned short*)(ws);      // reused as h1seq
    unsigned short* xi    = (unsigned short*)(ws + OFF_XI);
    unsigned short* Wib   = (unsigned short*)(ws + OFF_WIB);
    unsigned short* Whb   = (unsigned short*)(ws + OFF_WHB);
    unsigned short* hbufA = (unsigned short*)(ws + OFF_HBA);
    unsigned short* hbufB = (unsigned short*)(ws + OFF_HBB);
    unsigned int*   barA  = (unsigned int*)(ws + OFF_BRA);
    unsigned int*   barB  = (unsigned int*)(ws + OFF_BRB);

    const size_t SEQ = 33554432;                        // T*B*HC
    float* hs = out + SEQ;                              // [2,64,512]
    float* cs = out + SEQ + 65536;                      // [2,64,512]

    k_init_misc<<<2048, 256, 0, stream>>>(Wi, Wh, h0, Wib, Whb, hbufA, hbufB, barA, barB);
    k_convert_x<<<32768, 256, 0, stream>>>(x, xbf, 8388608);

    // layer 0
    k_gemm_bias<<<8192, 256, 0, stream>>>(xbf, Wib, bi, bh, xi);
    k_recur<<<256, 256, 0, stream>>>(Whb, xi, c0, hbufA, barA,
                                     /*seq_bf=*/xbf, /*seq_f32=*/nullptr,
                                     hs, cs);
    // layer 1
    k_gemm_bias<<<8192, 256, 0, stream>>>(xbf /*h1seq*/, Wib + 2048 * 512,
                                          bi + 2048, bh + 2048, xi);
    k_recur<<<256, 256, 0, stream>>>(Whb + 2048 * 512, xi, c0 + 32768, hbufB, barB,
                                     /*seq_bf=*/nullptr, /*seq_f32=*/out,
                                     hs + 32768, cs + 32768);
}

// Round 4
// 4938.716 us; speedup vs baseline: 11.0794x; 1.5404x over previous
//
#include <hip/hip_runtime.h>
#include <stdint.h>

// ---------------------------------------------------------------------------
// 2-layer LSTM, T=1024 B=64 IC=HC=512, fp32 in/out, bf16 MFMA internally.
//
//   1. k_init_misc : Wi/Wh -> bf16, hbuf(par0, slots0-7) <- h0[L0], zero flags
//   2. k_convert_x : x -> bf16
//   3. k_gemm_bias : xi1 = xbf @ Wi1^T + (bi1+bh1)   [bf16 out, 65536x2048]
//   4. k_recur2    : BOTH layers, software-pipelined: tick t computes
//                    h1(t) (L0) and h2(t-1) (L1). 1025 ticks instead of 2048.
//                    xi2 = Wi2*h1 computed on the fly (fp32 MFMA acc) -- the
//                    second GEMM dispatch and h1seq traffic are gone.
//
// R4 changes vs R3:
//   - merged layers, 1025 ticks (L1 lags L0 by one tick; exchange tile packs
//     h1(t-1) in MFMA rows 0-7, h2(t-2) in rows 8-15; ONE ds_read fragment
//     feeds 3 MFMA chains: Wh1*h1, Wi2*h1, Wh2*h2).
//   - NO acquire fence at all: h staging uses RELAXED agent atomic u64 loads
//     (MALL-direct, caches never involved -> nothing can be stale), then
//     ds_write into the swizzled LDS tile. Producer ordering = relaxed agent
//     atomic stores drained by __syncthreads' vmcnt(0) before the relaxed
//     flag store (R3-proven).
//   - weights for all 3 matmuls persist in VGPRs (48 bf16x8 frags/lane).
// ---------------------------------------------------------------------------

typedef __attribute__((ext_vector_type(8))) short  bf16x8;
typedef __attribute__((ext_vector_type(4))) float  f32x4;
typedef __attribute__((address_space(1))) const void* as1cv;
typedef __attribute__((address_space(3))) void*       as3v;

#define T_STEPS 1024
#define GATES   2048

__device__ __forceinline__ float bf2f(unsigned short u) {
    union { unsigned int i; float f; } v; v.i = ((unsigned int)u) << 16; return v.f;
}
__device__ __forceinline__ unsigned short f2bf(float f) {
    union { float f; unsigned int i; } v; v.f = f;
    unsigned int x = v.i;
    x += 0x7fffu + ((x >> 16) & 1u);   // RNE
    return (unsigned short)(x >> 16);
}
__device__ __forceinline__ float sigmoidf_fast(float x) {
    return 1.f / (1.f + __expf(-x));
}
__device__ __forceinline__ float tanhf_fast(float x) {
    float e2 = __expf(2.f * x);        // inf/0 saturate correctly to +-1
    return 1.f - 2.f / (e2 + 1.f);
}

// ---------------------------------------------------------------- init -----
__global__ __launch_bounds__(256) void k_init_misc(
    const float* __restrict__ Wi, const float* __restrict__ Wh,
    const float* __restrict__ h0,
    unsigned short* __restrict__ Wib, unsigned short* __restrict__ Whb,
    unsigned short* __restrict__ hbuf,   // [2 par][8 grp][16 slot][512]
    unsigned int* __restrict__ bar)      // [8][32][32]
{
    int i = blockIdx.x * 256 + threadIdx.x;          // 0 .. 524287
    if (i < 524288) {                                // 2*2048*512 / 4
        const float4* wi4 = (const float4*)Wi;
        const float4* wh4 = (const float4*)Wh;
        float4 a = wi4[i], b = wh4[i];
        ((ushort4*)Wib)[i] = make_ushort4(f2bf(a.x), f2bf(a.y), f2bf(a.z), f2bf(a.w));
        ((ushort4*)Whb)[i] = make_ushort4(f2bf(b.x), f2bf(b.y), f2bf(b.z), f2bf(b.w));
    }
    if (i < 32768) {                                 // hbuf par0 slots0-7 <- h0[L0]
        int bg = i >> 9, u = i & 511;                // global batch, unit
        int gg = bg >> 3, bb = bg & 7;
        hbuf[(size_t)gg * 8192 + bb * 512 + u] = f2bf(h0[bg * 512 + u]);
    }
    if (i < 8192) bar[i] = 0u;                       // zero flag array (32KB)
}

__global__ __launch_bounds__(256) void k_convert_x(
    const float* __restrict__ x, unsigned short* __restrict__ xbf, int n4)
{
    int i = blockIdx.x * 256 + threadIdx.x;
    if (i >= n4) return;
    float4 v = ((const float4*)x)[i];
    ((ushort4*)xbf)[i] = make_ushort4(f2bf(v.x), f2bf(v.y), f2bf(v.z), f2bf(v.w));
}

// ---------------------------------------------------------------- GEMM -----
// C[m][n] = sum_k A[m][k]*W[n][k] + bi[n] + bh[n];  A:[M][512], W:[2048][512]
// M=65536, N=2048, K=512. 128x128 tile, BK=64, 4 waves (2x2), 4x4 acc/wave.
__global__ __launch_bounds__(256) void k_gemm_bias(
    const unsigned short* __restrict__ A,
    const unsigned short* __restrict__ W,
    const float* __restrict__ bi, const float* __restrict__ bh,
    unsigned short* __restrict__ Cout)
{
    __shared__ unsigned short As[128 * 64];
    __shared__ unsigned short Bs[128 * 64];
    const int NB = GATES / 128;                      // 16
    int bn = blockIdx.x % NB, bm = blockIdx.x / NB;
    int m0 = bm * 128, n0 = bn * 128;
    int tid = threadIdx.x, lane = tid & 63, w = tid >> 6;
    int wr = w >> 1, wc = w & 1;

    f32x4 acc[4][4];
    #pragma unroll
    for (int a = 0; a < 4; ++a)
        #pragma unroll
        for (int b = 0; b < 4; ++b) { f32x4 z = {0.f,0.f,0.f,0.f}; acc[a][b] = z; }

    for (int kt = 0; kt < 8; ++kt) {
        int k0 = kt * 64;
        __syncthreads();                              // protect LDS reuse
        #pragma unroll
        for (int i = 0; i < 4; ++i) {                 // stage As (16 KB)
            int lin = (w * 4 + i) * 1024 + lane * 16; // byte pos
            int row = lin >> 7;
            int p   = (lin & 127) >> 4;
            int c   = p ^ (row & 7);
            const unsigned short* ga = A + (size_t)(m0 + row) * 512 + k0 + c * 8;
            __builtin_amdgcn_global_load_lds((as1cv)ga, (as3v)((char*)As + lin), 16, 0, 0);
        }
        #pragma unroll
        for (int i = 0; i < 4; ++i) {                 // stage Bs (16 KB)
            int lin = (w * 4 + i) * 1024 + lane * 16;
            int row = lin >> 7;
            int p   = (lin & 127) >> 4;
            int c   = p ^ (row & 7);
            const unsigned short* gb = W + (size_t)(n0 + row) * 512 + k0 + c * 8;
            __builtin_amdgcn_global_load_lds((as1cv)gb, (as3v)((char*)Bs + lin), 16, 0, 0);
        }
        __syncthreads();
        #pragma unroll
        for (int ks = 0; ks < 2; ++ks) {
            bf16x8 af[4], bfr[4];
            #pragma unroll
            for (int mt = 0; mt < 4; ++mt) {
                int row = wr * 64 + mt * 16 + (lane & 15);
                int p = (ks * 4 + (lane >> 4)) ^ (row & 7);
                af[mt] = *(const bf16x8*)(&As[row * 64 + p * 8]);
            }
            #pragma unroll
            for (int nt = 0; nt < 4; ++nt) {
                int row = wc * 64 + nt * 16 + (lane & 15);
                int p = (ks * 4 + (lane >> 4)) ^ (row & 7);
                bfr[nt] = *(const bf16x8*)(&Bs[row * 64 + p * 8]);
            }
            #pragma unroll
            for (int mt = 0; mt < 4; ++mt)
                #pragma unroll
                for (int nt = 0; nt < 4; ++nt)
                    acc[mt][nt] = __builtin_amdgcn_mfma_f32_16x16x32_bf16(
                        af[mt], bfr[nt], acc[mt][nt], 0, 0, 0);
        }
    }
    // epilogue: C row = (lane>>4)*4+reg, col = lane&15  [m89-verified]
    #pragma unroll
    for (int nt = 0; nt < 4; ++nt) {
        int n = n0 + wc * 64 + nt * 16 + (lane & 15);
        float bias = bi[n] + bh[n];
        #pragma unroll
        for (int mt = 0; mt < 4; ++mt) {
            #pragma unroll
            for (int r = 0; r < 4; ++r) {
                int m = m0 + wr * 64 + mt * 16 + (lane >> 4) * 4 + r;
                Cout[(size_t)m * GATES + n] = f2bf(acc[mt][nt][r] + bias);
            }
        }
    }
}

// -------------------------------------------------------- merged recur -----
// grid 256: group g = blockIdx&7 (8 batches), j = blockIdx>>3 (16 units).
// Tick t: L0 computes h1(t) (t<T); L1 computes h2(t-1) (t>=1). 1025 ticks.
// Exchange tile tC: rows 0-7 = h1(t-1) batches, rows 8-15 = h2(t-2) batches.
__global__ __launch_bounds__(256, 1) void k_recur2(
    const unsigned short* __restrict__ Wh1b,  // [2048][512] L0 recurrent
    const unsigned short* __restrict__ Wi2b,  // [2048][512] L1 input
    const unsigned short* __restrict__ Wh2b,  // [2048][512] L1 recurrent
    const unsigned short* __restrict__ xi1,   // [T*64][2048] bf16 (L0 bias folded)
    const float* __restrict__ b2i, const float* __restrict__ b2h, // L1 biases [2048]
    const float* __restrict__ h0, const float* __restrict__ c0,   // [2][64][512]
    unsigned short* __restrict__ hbuf,        // [2 par][8 grp][16 slot][512]
    unsigned int* __restrict__ bar,           // [8 grp][32 blk][32 u32 pad]
    float* __restrict__ seq,                  // [T][64][512] h2 (d_out)
    float* __restrict__ hT, float* __restrict__ cT)   // [2][64][512]
{
    __shared__ unsigned short tC[16 * 512];   // packed swizzled exchange tile
    __shared__ float gA0[4][8][17];           // gates1 = Wh1*h1   (rows 0-7)
    __shared__ float gA1[4][8][17];           // Wi2*h1            (rows 0-7)
    __shared__ float gA2[4][8][17];           // Wh2*h2            (rows 8-15)

    const int g = blockIdx.x & 7;
    const int j = blockIdx.x >> 3;
    const int tid = threadIdx.x;
    const int lane = tid & 63;
    const int w = tid >> 6;                   // wave == gate segment

    // Persistent weight fragments: wave w, units 16j..16j+15, seg w, all K.
    bf16x8 w0[16], w1[16], w2[16];
    {
        int n = lane & 15;
        size_t rowW = (size_t)(w * 512 + 16 * j + n) * 512 + (lane >> 4) * 8;
        #pragma unroll
        for (int ks = 0; ks < 16; ++ks) {
            w0[ks] = *(const bf16x8*)(Wh1b + rowW + ks * 32);
            w1[ks] = *(const bf16x8*)(Wi2b + rowW + ks * 32);
            w2[ks] = *(const bf16x8*)(Wh2b + rowW + ks * 32);
        }
    }

    // elementwise state (threads 0..127): one (unit,batch) per thread
    const int pb = (tid >> 4) & 7;            // local batch 0..7
    const int pu = tid & 15;                  // local unit 0..15
    const int bglob = 8 * g + pb;
    const int uglob = 16 * j + pu;
    float c1 = 0.f, c2 = 0.f, h2init = 0.f;
    float bs2[4] = {0.f, 0.f, 0.f, 0.f};
    unsigned short xc0 = 0, xc1 = 0, xc2 = 0, xc3 = 0;
    if (tid < 128) {
        c1     = c0[bglob * 512 + uglob];
        c2     = c0[32768 + bglob * 512 + uglob];
        h2init = h0[32768 + bglob * 512 + uglob];
        #pragma unroll
        for (int s = 0; s < 4; ++s)
            bs2[s] = b2i[s * 512 + uglob] + b2h[s * 512 + uglob];
        const unsigned short* xr = xi1 + (size_t)bglob * GATES;
        xc0 = xr[uglob]; xc1 = xr[512 + uglob]; xc2 = xr[1024 + uglob]; xc3 = xr[1536 + uglob];
    }

    unsigned int* gbf  = bar + g * 1024;      // this group's 32 flags (128B apart)
    unsigned int* myfl = gbf + j * 32;

    for (int t = 0; ; ++t) {
        const int pr = t & 1;

        // [A] stage packed tile (16KB): relaxed agent u64 loads (MALL-direct,
        // no caches -> no staleness, no fence) + swizzled ds_write_b64.
        {
            const char* src = (const char*)(hbuf + ((size_t)pr * 8 + g) * 8192);
            #pragma unroll
            for (int l = 0; l < 8; ++l) {
                int gofs = l * 2048 + tid * 8;          // byte pos in 16KB
                int row  = gofs >> 10;
                int cg   = (gofs & 1023) >> 4;
                int half = gofs & 8;
                int lofs = row * 1024 + ((cg ^ (row & 7)) << 4) + half;
                unsigned long long v = __hip_atomic_load(
                    (unsigned long long*)(src + gofs),
                    __ATOMIC_RELAXED, __HIP_MEMORY_SCOPE_AGENT);
                *(unsigned long long*)((char*)tC + lofs) = v;
            }
        }
        __syncthreads();                      // [B] staging visible block-wide

        // [C] MFMA: one fragment load feeds 3 chains (16 frags, 48 MFMA)
        {
            f32x4 a0 = {0.f,0.f,0.f,0.f};
            f32x4 a1 = {0.f,0.f,0.f,0.f};
            f32x4 a2 = {0.f,0.f,0.f,0.f};
            int m = lane & 15;
            #pragma unroll
            for (int ks = 0; ks < 16; ++ks) {
                int p = (ks * 4 + (lane >> 4)) ^ (m & 7);
                bf16x8 fr = *(const bf16x8*)(&tC[m * 512 + p * 8]);
                a0 = __builtin_amdgcn_mfma_f32_16x16x32_bf16(fr, w0[ks], a0, 0, 0, 0);
                a1 = __builtin_amdgcn_mfma_f32_16x16x32_bf16(fr, w1[ks], a1, 0, 0, 0);
                a2 = __builtin_amdgcn_mfma_f32_16x16x32_bf16(fr, w2[ks], a2, 0, 0, 0);
            }
            int r0 = (lane >> 4) * 4, ncol = lane & 15;
            if (lane < 32) {                  // C rows 0-7: h1-derived results
                #pragma unroll
                for (int r = 0; r < 4; ++r) {
                    gA0[w][r0 + r][ncol] = a0[r];
                    gA1[w][r0 + r][ncol] = a1[r];
                }
            } else {                          // C rows 8-15: h2-derived results
                #pragma unroll
                for (int r = 0; r < 4; ++r)
                    gA2[w][r0 - 8 + r][ncol] = a2[r];
            }
        }
        __syncthreads();                      // [D]

        // [E] elementwise: L0 tick t, L1 tick t-1; relaxed agent h stores
        float h1v = 0.f, h2v = 0.f;
        unsigned short* dst = hbuf + ((size_t)(pr ^ 1) * 8 + g) * 8192;
        if (tid < 128) {
            if (t < T_STEPS) {
                float fg = sigmoidf_fast(gA0[0][pb][pu] + bf2f(xc0));
                float ig = sigmoidf_fast(gA0[1][pb][pu] + bf2f(xc1));
                float og = sigmoidf_fast(gA0[2][pb][pu] + bf2f(xc2));
                float gg = tanhf_fast(gA0[3][pb][pu] + bf2f(xc3));
                c1 = c1 * fg + gg * ig;
                h1v = og * tanhf_fast(c1);
                __hip_atomic_store(&dst[pb * 512 + uglob], f2bf(h1v),
                                   __ATOMIC_RELAXED, __HIP_MEMORY_SCOPE_AGENT);
            }
            if (t == 0) {
                h2v = h2init;                 // seed h2(-1) = h0[L1]
                __hip_atomic_store(&dst[(8 + pb) * 512 + uglob], f2bf(h2v),
                                   __ATOMIC_RELAXED, __HIP_MEMORY_SCOPE_AGENT);
            } else {
                float fg = sigmoidf_fast(gA1[0][pb][pu] + gA2[0][pb][pu] + bs2[0]);
                float ig = sigmoidf_fast(gA1[1][pb][pu] + gA2[1][pb][pu] + bs2[1]);
                float og = sigmoidf_fast(gA1[2][pb][pu] + gA2[2][pb][pu] + bs2[2]);
                float gg = tanhf_fast(gA1[3][pb][pu] + gA2[3][pb][pu] + bs2[3]);
                c2 = c2 * fg + gg * ig;
                h2v = og * tanhf_fast(c2);
                if (t < T_STEPS)
                    __hip_atomic_store(&dst[(8 + pb) * 512 + uglob], f2bf(h2v),
                                       __ATOMIC_RELAXED, __HIP_MEMORY_SCOPE_AGENT);
                seq[(size_t)(t - 1) * 32768 + bglob * 512 + uglob] = h2v;
            }
            if (t == T_STEPS - 1) {           // L0 finals
                hT[bglob * 512 + uglob] = h1v;
                cT[bglob * 512 + uglob] = c1;
            }
            if (t == T_STEPS) {               // L1 finals
                hT[32768 + bglob * 512 + uglob] = h2v;
                cT[32768 + bglob * 512 + uglob] = c2;
            }
        }
        if (t == T_STEPS) break;              // uniform; no barrier needed after

        __syncthreads();                      // [F] vmcnt(0): h stores acked at MALL

        // [G] arrive: bare write-through flag store
        if (tid == 0)
            __hip_atomic_store(myfl, (unsigned int)(t + 1), __ATOMIC_RELAXED,
                               __HIP_MEMORY_SCOPE_AGENT);

        // [H] next-tick xi prefetch, in flight during the barrier wait
        unsigned short xn0 = 0, xn1 = 0, xn2 = 0, xn3 = 0;
        if (tid < 128) {
            int tn = (t + 1 < T_STEPS) ? t + 1 : T_STEPS - 1;
            const unsigned short* xr = xi1 + (size_t)(tn * 64 + bglob) * GATES;
            xn0 = xr[uglob]; xn1 = xr[512 + uglob]; xn2 = xr[1024 + uglob]; xn3 = xr[1536 + uglob];
        }

        // [I] wait: wave 0 polls all 32 flags with RELAXED loads (no inv)
        if (tid < 64) {
            const unsigned int tgt = (unsigned int)(t + 1);
            unsigned int* fl = gbf + (tid & 31) * 32;
            while (__hip_atomic_load(fl, __ATOMIC_RELAXED,
                                     __HIP_MEMORY_SCOPE_AGENT) < tgt) {
                __builtin_amdgcn_s_sleep(1);
            }
        }
        if (tid < 128) { xc0 = xn0; xc1 = xn1; xc2 = xn2; xc3 = xn3; }
        __syncthreads();                      // [J]
    }
}

// --------------------------------------------------------------- launch ----
extern "C" void kernel_launch(void* const* d_in, const int* in_sizes, int n_in,
                              void* d_out, int out_size, void* d_ws, size_t ws_size,
                              hipStream_t stream)
{
    (void)in_sizes; (void)n_in; (void)out_size; (void)ws_size;
    const float* x  = (const float*)d_in[0];   // [1024,64,512]
    const float* Wi = (const float*)d_in[1];   // [2,2048,512]
    const float* bi = (const float*)d_in[2];   // [2,2048]
    const float* Wh = (const float*)d_in[3];   // [2,2048,512]
    const float* bh = (const float*)d_in[4];   // [2,2048]
    const float* h0 = (const float*)d_in[5];   // [2,64,512]
    const float* c0 = (const float*)d_in[6];   // [2,64,512]
    float* out = (float*)d_out;

    char* ws = (char*)d_ws;
    const size_t OFF_XI  = 67108864;                    // xbf: 64 MB
    const size_t OFF_WIB = OFF_XI  + 268435456;         // xi1: 256 MB
    const size_t OFF_WHB = OFF_WIB + 4194304;
    const size_t OFF_HB  = OFF_WHB + 4194304;
    const size_t OFF_BAR = OFF_HB  + 262144;            // hbuf 256 KB, bar 32 KB

    unsigned short* xbf  = (unsigned short*)(ws);
    unsigned short* xi1  = (unsigned short*)(ws + OFF_XI);
    unsigned short* Wib  = (unsigned short*)(ws + OFF_WIB);
    unsigned short* Whb  = (unsigned short*)(ws + OFF_WHB);
    unsigned short* hbuf = (unsigned short*)(ws + OFF_HB);
    unsigned int*   bar  = (unsigned int*)(ws + OFF_BAR);

    const size_t SEQ = 33554432;                        // T*B*HC
    float* hs = out + SEQ;                              // [2,64,512]
    float* cs = out + SEQ + 65536;                      // [2,64,512]

    k_init_misc<<<2048, 256, 0, stream>>>(Wi, Wh, h0, Wib, Whb, hbuf, bar);
    k_convert_x<<<32768, 256, 0, stream>>>(x, xbf, 8388608);

    // xi1 = x @ Wi1^T + (bi1+bh1)
    k_gemm_bias<<<8192, 256, 0, stream>>>(xbf, Wib, bi, bh, xi1);

    // both layers, pipelined
    k_recur2<<<256, 256, 0, stream>>>(Whb,                 // Wh1
                                      Wib + 2048 * 512,    // Wi2
                                      Whb + 2048 * 512,    // Wh2
                                      xi1,
                                      bi + 2048, bh + 2048,
                                      h0, c0,
                                      hbuf, bar,
                                      out, hs, cs);
}